// Round 1
// baseline (143.044 us; speedup 1.0000x reference)
//
#include <hip/hip_runtime.h>
#include <stdint.h>

// Chain min-cut / Viterbi. Exact fp32 emulation of the reference scan via
// scalar d-recurrence (d = a0 - a1 of the renormalized carry), parallelized
// with monotone-sandwich segment summaries + event/sign bitmask backward fill.

#define LAM 0.75f
constexpr int N_TOTAL = 8388608;
constexpr int SEG_LEN = 128;
constexpr int NSEG = N_TOTAL / SEG_LEN;   // 65536
constexpr int NWORD = N_TOTAL / 64;       // 131072

// Bit-exact renormalized step: d' = fl(fl(p+e0) - fl(fl(1-p)+e1))
__device__ __forceinline__ float dstep(float d, float p) {
    float e0 = fminf(fmaxf(d, 0.0f), LAM);
    float e1 = fminf(fmaxf(-d, 0.0f), LAM);
    return (p + e0) - ((1.0f - p) + e1);
}

// K1: per-segment summary. Segment s>=1 owns steps j in [s*L, s*L+L-1],
// mapping d_{sL-1} -> d_{sL+L-1}. Run from extremes +-2 (monotone sandwich);
// if they coalesce bitwise the segment map is an exact constant.
// Segment 0 is run exactly (known initial carry, special first step).
__global__ __launch_bounds__(256) void k_summary(const float* __restrict__ p,
        float* __restrict__ val, uint32_t* __restrict__ isc) {
    int s = blockIdx.x * blockDim.x + threadIdx.x;
    if (s >= NSEG) return;
    const float* seg = p + (size_t)s * SEG_LEN;
    if (s == 0) {
        float p0 = seg[0];
        float a0 = p0, a1 = 1.0f - p0;          // non-renormalized init carry
        float t0 = fminf(a0, a1 + LAM);
        float t1 = fminf(a1, a0 + LAM);
        float p1 = seg[1];
        float d = (p1 + t0) - ((1.0f - p1) + t1);  // d_1 (renormalized)
        for (int i = 2; i < SEG_LEN; ++i) d = dstep(d, seg[i]);
        val[0] = d;
        isc[0] = 1u;
        return;
    }
    const float4* seg4 = (const float4*)seg;
    float dh = 2.0f, dl = -2.0f;
    float4 q0 = seg4[0], q1 = seg4[1];
    #pragma unroll 4
    for (int i = 0; i < SEG_LEN / 4; ++i) {
        float4 qn = (i + 2 < SEG_LEN / 4) ? seg4[i + 2] : q0;
        dh = dstep(dh, q0.x); dl = dstep(dl, q0.x);
        dh = dstep(dh, q0.y); dl = dstep(dl, q0.y);
        dh = dstep(dh, q0.z); dl = dstep(dl, q0.z);
        dh = dstep(dh, q0.w); dl = dstep(dl, q0.w);
        q0 = q1; q1 = qn;
    }
    val[s] = dh;
    isc[s] = (dh == dl) ? 1u : 0u;
}

// K2: resolve exact entry d per segment (walk back to nearest constant
// summary; replay any non-constant predecessors exactly — rare), then re-run
// the segment emitting per-position event (|d|>lam) and sign (d>lam) bits.
// Position N-1 gets a forced event with sign = final label (d_{N-1} > 0).
__global__ __launch_bounds__(256) void k_classify(const float* __restrict__ p,
        const float* __restrict__ val, const uint32_t* __restrict__ isc,
        uint64_t* __restrict__ ev, uint64_t* __restrict__ sg) {
    int s = blockIdx.x * blockDim.x + threadIdx.x;
    if (s >= NSEG) return;
    const float* seg = p + (size_t)s * SEG_LEN;

    if (s == 0) {
        uint64_t ew0 = 0, gw0 = 0, ew1 = 0, gw1 = 0;
        float p0 = seg[0];
        float a0 = p0, a1 = 1.0f - p0;
        bool f1 = (a1 + LAM) < a0;              // node-0 decisions (non-renorm)
        bool f0 = (a0 + LAM) < a1;
        if (f1 || f0) { ew0 |= 1ull; if (f1) gw0 |= 1ull; }
        float t0 = fminf(a0, a1 + LAM);
        float t1 = fminf(a1, a0 + LAM);
        float p1 = seg[1];
        float d = (p1 + t0) - ((1.0f - p1) + t1);  // d_1
        { bool s1 = d > LAM, s0 = d < -LAM;
          if (s1 || s0) { ew0 |= 2ull; if (s1) gw0 |= 2ull; } }
        for (int i = 2; i < SEG_LEN; ++i) {
            d = dstep(d, seg[i]);
            bool c1 = d > LAM, c0 = d < -LAM;
            uint64_t b = 1ull << (i & 63);
            if (i < 64) { if (c1 || c0) ew0 |= b; if (c1) gw0 |= b; }
            else        { if (c1 || c0) ew1 |= b; if (c1) gw1 |= b; }
        }
        ev[0] = ew0; ev[1] = ew1; sg[0] = gw0; sg[1] = gw1;
        return;
    }

    // Resolve exact entry d_{sL-1}
    int t = s - 1;
    while (isc[t] == 0u) --t;                   // terminates: isc[0]==1
    float d = val[t];
    for (int u = t + 1; u < s; ++u) {           // exact replay (rare path)
        const float* su = p + (size_t)u * SEG_LEN;
        for (int i = 0; i < SEG_LEN; ++i) d = dstep(d, su[i]);
    }

    const float4* seg4 = (const float4*)seg;
    uint64_t ew0 = 0, gw0 = 0, ew1 = 0, gw1 = 0;
    float4 q0 = seg4[0], q1 = seg4[1];
    #pragma unroll 8
    for (int i = 0; i < 32; ++i) {
        float4 qn = (i + 2 < 32) ? seg4[i + 2] : q0;
        uint64_t e = 0, g = 0;
        d = dstep(d, q0.x); e |= (uint64_t)(d > LAM || d < -LAM);      g |= (uint64_t)(d > LAM);
        d = dstep(d, q0.y); e |= (uint64_t)(d > LAM || d < -LAM) << 1; g |= (uint64_t)(d > LAM) << 1;
        d = dstep(d, q0.z); e |= (uint64_t)(d > LAM || d < -LAM) << 2; g |= (uint64_t)(d > LAM) << 2;
        d = dstep(d, q0.w); e |= (uint64_t)(d > LAM || d < -LAM) << 3; g |= (uint64_t)(d > LAM) << 3;
        int sh = (4 * i) & 63;
        if (i < 16) { ew0 |= e << sh; gw0 |= g << sh; }
        else        { ew1 |= e << sh; gw1 |= g << sh; }
        q0 = q1; q1 = qn;
    }
    if (s == NSEG - 1) {                        // forced event at N-1: final label
        const uint64_t top = 1ull << 63;
        ew1 |= top;
        gw1 = (d > 0.0f) ? (gw1 | top) : (gw1 & ~top);
    }
    ev[2 * (size_t)s] = ew0; ev[2 * (size_t)s + 1] = ew1;
    sg[2 * (size_t)s] = gw0; sg[2 * (size_t)s + 1] = gw1;
}

// K3: label_j = sign of first event at k >= j. One thread per 64-bit word;
// incoming label from the first nonzero event word to the right (guaranteed
// to exist: word NWORD-1 has bit 63 set).
__global__ __launch_bounds__(256) void k_fill(const uint64_t* __restrict__ ev,
        const uint64_t* __restrict__ sg, int* __restrict__ out) {
    int w = blockIdx.x * blockDim.x + threadIdx.x;
    if (w >= NWORD) return;
    int cur = 0;
    if (w + 1 < NWORD) {
        int v = w + 1;
        uint64_t e = ev[v];
        while (e == 0ull) { ++v; e = ev[v]; }
        int i = __builtin_ctzll(e);
        cur = (int)((sg[v] >> i) & 1ull);
    }
    uint64_t e = ev[w], g = sg[w];
    int4* o4 = (int4*)(out + (size_t)w * 64);
    #pragma unroll
    for (int k = 15; k >= 0; --k) {
        int l[4];
        #pragma unroll
        for (int b = 3; b >= 0; --b) {
            int i = 4 * k + b;
            if ((e >> i) & 1ull) cur = (int)((g >> i) & 1ull);
            l[b] = cur;
        }
        o4[k] = make_int4(l[0], l[1], l[2], l[3]);
    }
}

extern "C" void kernel_launch(void* const* d_in, const int* in_sizes, int n_in,
                              void* d_out, int out_size, void* d_ws, size_t ws_size,
                              hipStream_t stream) {
    (void)in_sizes; (void)n_in; (void)out_size; (void)ws_size;
    const float* p = (const float*)d_in[0];
    int* out = (int*)d_out;
    char* ws = (char*)d_ws;
    float*    val = (float*)ws;                                   // 256 KB
    uint32_t* isc = (uint32_t*)(ws + (size_t)NSEG * 4);           // 256 KB
    uint64_t* ev  = (uint64_t*)(ws + (size_t)NSEG * 8);           // 1 MB
    uint64_t* sg  = (uint64_t*)(ws + (size_t)NSEG * 8 + (size_t)NWORD * 8); // 1 MB

    k_summary<<<dim3(NSEG / 256), dim3(256), 0, stream>>>(p, val, isc);
    k_classify<<<dim3(NSEG / 256), dim3(256), 0, stream>>>(p, val, isc, ev, sg);
    k_fill<<<dim3(NWORD / 256), dim3(256), 0, stream>>>(ev, sg, out);
}

// Round 2
// 117.742 us; speedup vs baseline: 1.2149x; 1.2149x over previous
//
#include <hip/hip_runtime.h>
#include <stdint.h>

// Chain min-cut / Viterbi, exact fp32 emulation of the reference scan via the
// scalar d-recurrence (d = a0 - a1 of the renormalized carry).
// Round 2: SEG=64 (1 segment == one 64-bit event word), full register preload
// of each thread's segment (16 independent float4 loads) for BW-bound staging,
// 8 waves/CU occupancy.

#define LAM 0.75f
constexpr int N_TOTAL = 8388608;
constexpr int SEG = 64;
constexpr int NSEG = N_TOTAL / SEG;   // 131072 segments == 64-bit words
constexpr int NBLK = NSEG / 256;      // 512 blocks

// Bit-exact renormalized step: d' = fl(fl(p+e0) - fl(fl(1-p)+e1))
__device__ __forceinline__ float dstep(float d, float p) {
    float e0 = fminf(fmaxf(d, 0.0f), LAM);
    float e1 = fminf(fmaxf(-d, 0.0f), LAM);
    return (p + e0) - ((1.0f - p) + e1);
}

union SegU { float4 q[16]; float f[64]; };

// K1: per-segment summary. Segment s>=1 maps d_{64s-1} -> d_{64s+63}; run from
// extremes +-2 (the step map is monotone in d and forgets its input once the
// clamp saturates) -> if hi/lo coalesce bitwise, the map is an exact constant.
// Segment 0 is run exactly from the known initial carry.
__global__ __launch_bounds__(256) void k_summary(const float* __restrict__ p,
        float* __restrict__ val, uint32_t* __restrict__ isc) {
    int s = blockIdx.x * 256 + threadIdx.x;
    SegU u;
    const float4* g = (const float4*)(p + (size_t)s * SEG);
    #pragma unroll
    for (int i = 0; i < 16; ++i) u.q[i] = g[i];   // 16 independent loads, issued up front

    if (s == 0) {
        float p0 = u.f[0];
        float a0 = p0, a1 = 1.0f - p0;            // non-renormalized init carry
        float t0 = fminf(a0, a1 + LAM);
        float t1 = fminf(a1, a0 + LAM);
        float p1 = u.f[1];
        float d = (p1 + t0) - ((1.0f - p1) + t1); // d_1 (renormalized)
        #pragma unroll
        for (int i = 2; i < 64; ++i) d = dstep(d, u.f[i]);
        val[0] = d;
        isc[0] = 1u;
        return;
    }
    float dh = 2.0f, dl = -2.0f;
    #pragma unroll
    for (int i = 0; i < 64; ++i) { dh = dstep(dh, u.f[i]); dl = dstep(dl, u.f[i]); }
    val[s] = dh;
    isc[s] = (dh == dl) ? 1u : 0u;
}

// K2: resolve the exact entry d per segment (predecessor's constant summary;
// rare non-constant predecessors replayed exactly from global), then run the
// segment emitting per-node event (|d|>lam) and sign (d>lam) bits.
// Node N-1 gets a forced event with sign = final label (d_{N-1} > 0).
__global__ __launch_bounds__(256) void k_classify(const float* __restrict__ p,
        const float* __restrict__ val, const uint32_t* __restrict__ isc,
        uint64_t* __restrict__ ev, uint64_t* __restrict__ sg) {
    int s = blockIdx.x * 256 + threadIdx.x;
    SegU u;
    const float4* g = (const float4*)(p + (size_t)s * SEG);
    #pragma unroll
    for (int i = 0; i < 16; ++i) u.q[i] = g[i];

    uint64_t e = 0, gw = 0;
    float d;
    if (s == 0) {
        float p0 = u.f[0];
        float a0 = p0, a1 = 1.0f - p0;
        bool f1 = (a1 + LAM) < a0;                // node-0 decisions (non-renorm carry)
        bool f0 = (a0 + LAM) < a1;
        e |= (uint64_t)(f1 || f0); gw |= (uint64_t)f1;
        float t0 = fminf(a0, a1 + LAM);
        float t1 = fminf(a1, a0 + LAM);
        float p1 = u.f[1];
        d = (p1 + t0) - ((1.0f - p1) + t1);       // d_1
        e |= (uint64_t)(d > LAM || d < -LAM) << 1;
        gw |= (uint64_t)(d > LAM) << 1;
        #pragma unroll
        for (int i = 2; i < 64; ++i) {
            d = dstep(d, u.f[i]);
            e  |= (uint64_t)(d > LAM || d < -LAM) << i;
            gw |= (uint64_t)(d > LAM) << i;
        }
    } else {
        int t = s - 1;
        while (isc[t] == 0u) --t;                 // terminates: isc[0]==1
        d = val[t];
        for (int v = t + 1; v < s; ++v) {         // exact replay (rare path)
            const float* sv = p + (size_t)v * SEG;
            for (int i = 0; i < SEG; ++i) d = dstep(d, sv[i]);
        }
        #pragma unroll
        for (int i = 0; i < 64; ++i) {
            d = dstep(d, u.f[i]);
            e  |= (uint64_t)(d > LAM || d < -LAM) << i;
            gw |= (uint64_t)(d > LAM) << i;
        }
    }
    if (s == NSEG - 1) {                          // forced event at N-1: final label
        const uint64_t top = 1ull << 63;
        e |= top;
        gw = (d > 0.0f) ? (gw | top) : (gw & ~top);
    }
    ev[s] = e;
    sg[s] = gw;
}

// K3: label_j = sign of the first event at k >= j. One thread per 64-bit word;
// incoming label from the first nonzero event word to the right (guaranteed:
// word NSEG-1 has bit 63 forced).
__global__ __launch_bounds__(256) void k_fill(const uint64_t* __restrict__ ev,
        const uint64_t* __restrict__ sg, int* __restrict__ out) {
    int w = blockIdx.x * 256 + threadIdx.x;
    int cur = 0;
    if (w + 1 < NSEG) {
        int v = w + 1;
        uint64_t e = ev[v];
        while (e == 0ull) { ++v; e = ev[v]; }     // P(empty word) ~ 1e-8
        int i = __builtin_ctzll(e);
        cur = (int)((sg[v] >> i) & 1ull);
    }
    uint64_t e = ev[w], g = sg[w];
    int4* o4 = (int4*)(out + (size_t)w * 64);
    #pragma unroll
    for (int k = 15; k >= 0; --k) {
        int4 r;
        int i3 = 4 * k + 3; if ((e >> i3) & 1ull) cur = (int)((g >> i3) & 1ull); r.w = cur;
        int i2 = 4 * k + 2; if ((e >> i2) & 1ull) cur = (int)((g >> i2) & 1ull); r.z = cur;
        int i1 = 4 * k + 1; if ((e >> i1) & 1ull) cur = (int)((g >> i1) & 1ull); r.y = cur;
        int i0 = 4 * k + 0; if ((e >> i0) & 1ull) cur = (int)((g >> i0) & 1ull); r.x = cur;
        o4[k] = r;
    }
}

extern "C" void kernel_launch(void* const* d_in, const int* in_sizes, int n_in,
                              void* d_out, int out_size, void* d_ws, size_t ws_size,
                              hipStream_t stream) {
    (void)in_sizes; (void)n_in; (void)out_size; (void)ws_size;
    const float* p = (const float*)d_in[0];
    int* out = (int*)d_out;
    char* ws = (char*)d_ws;
    float*    val = (float*)ws;                                    // 512 KB
    uint32_t* isc = (uint32_t*)(ws + (size_t)NSEG * 4);            // 512 KB
    uint64_t* ev  = (uint64_t*)(ws + (size_t)NSEG * 8);            // 1 MB
    uint64_t* sg  = (uint64_t*)(ws + (size_t)NSEG * 16);           // 1 MB

    k_summary<<<dim3(NBLK), dim3(256), 0, stream>>>(p, val, isc);
    k_classify<<<dim3(NBLK), dim3(256), 0, stream>>>(p, val, isc, ev, sg);
    k_fill<<<dim3(NBLK), dim3(256), 0, stream>>>(ev, sg, out);
}

// Round 3
// 89.411 us; speedup vs baseline: 1.5998x; 1.3169x over previous
//
#include <hip/hip_runtime.h>
#include <stdint.h>

// Chain min-cut / Viterbi, exact fp32 emulation of the reference scan via the
// scalar d-recurrence (d = a0 - a1 of the renormalized carry).
// Round 3: fused summary+classify kernel (input read ONCE, segment held in
// registers across both phases; cross-segment entry resolved block-locally via
// LDS, cross-block via tiny redundant recompute) + coalesced ctz-based fill.

#define LAM 0.75f
constexpr int N_TOTAL = 8388608;
constexpr int SEG = 64;
constexpr int NSEG = N_TOTAL / SEG;   // 131072 segments == 64-bit words
constexpr int NBLK = NSEG / 256;      // 512 blocks

// Bit-exact renormalized step: d' = fl(fl(p+e0) - fl(fl(1-p)+e1))
__device__ __forceinline__ float dstep(float d, float p) {
    float e0 = fminf(fmaxf(d, 0.0f), LAM);
    float e1 = fminf(fmaxf(-d, 0.0f), LAM);
    return (p + e0) - ((1.0f - p) + e1);
}

// Exact d at the END of segment 0 (special non-renormalized first step).
__device__ float seg0_end(const float* __restrict__ p) {
    float p0 = p[0];
    float a0 = p0, a1 = 1.0f - p0;
    float t0 = fminf(a0, a1 + LAM);
    float t1 = fminf(a1, a0 + LAM);
    float p1 = p[1];
    float d = (p1 + t0) - ((1.0f - p1) + t1);   // d_1 (renormalized)
    for (int i = 2; i < 64; ++i) d = dstep(d, p[i]);
    return d;
}

union SegU { float4 q[16]; float f[64]; };

// Fused K1+K2: each thread owns one 64-node segment (held in registers).
// Phase A: monotone hi/lo sandwich summary -> LDS. The step map forgets its
// input once the clamp saturates, so hi==lo (bitwise) => exact constant map.
// Phase B: entry d from predecessor lane's constant summary (LDS walk-back;
// rare exact replays from L1/L2-hot global). Lane 0 recomputes predecessor
// block's summaries from global (256 B each, rare >1). Then classify: emit
// per-node event (|d|>lam) / sign (d>lam) bits from the register-held segment.
__global__ __launch_bounds__(256) void k_ab(const float* __restrict__ p,
        uint64_t* __restrict__ ev, uint64_t* __restrict__ sg) {
    __shared__ float s_dh[256];
    __shared__ uint8_t s_ok[256];
    const int t = threadIdx.x;
    const int s = blockIdx.x * 256 + t;

    SegU u;
    const float4* g4 = (const float4*)(p + (size_t)s * SEG);
    #pragma unroll
    for (int i = 0; i < 16; ++i) u.q[i] = g4[i];  // 16 independent loads up front

    // Phase A: sandwich summary
    float dh = 2.0f, dl = -2.0f;
    #pragma unroll
    for (int i = 0; i < 64; ++i) {
        float pi = u.f[i];
        dh = dstep(dh, pi);
        dl = dstep(dl, pi);
    }
    s_dh[t] = dh;
    s_ok[t] = (dh == dl) ? 1 : 0;
    __syncthreads();

    // Phase B: resolve exact entry d (= d at end of segment s-1)
    float d = 0.0f;
    uint64_t e = 0, gw = 0;
    if (s == 0) {
        float p0 = u.f[0];
        float a0 = p0, a1 = 1.0f - p0;
        bool f1 = (a1 + LAM) < a0;                // node-0 decisions (non-renorm)
        bool f0 = (a0 + LAM) < a1;
        e |= (uint64_t)(f1 || f0); gw |= (uint64_t)f1;
        float t0 = fminf(a0, a1 + LAM);
        float t1 = fminf(a1, a0 + LAM);
        float p1 = u.f[1];
        d = (p1 + t0) - ((1.0f - p1) + t1);       // d_1
        e |= (uint64_t)(d > LAM || d < -LAM) << 1;
        gw |= (uint64_t)(d > LAM) << 1;
        #pragma unroll
        for (int i = 2; i < 64; ++i) {
            d = dstep(d, u.f[i]);
            e  |= (uint64_t)(d > LAM || d < -LAM) << i;
            gw |= (uint64_t)(d > LAM) << i;
        }
    } else {
        int back = t - 1;
        while (back >= 0 && !s_ok[back]) --back;  // common: stops immediately
        int startSeg;
        if (back >= 0) {
            d = s_dh[back];
            startSeg = blockIdx.x * 256 + back;
        } else {
            // cross-block: recompute predecessor summaries from global (rare >1 iter)
            int v = blockIdx.x * 256 - 1;
            for (;;) {
                if (v == 0) { d = seg0_end(p); startSeg = 0; break; }
                const float4* gv = (const float4*)(p + (size_t)v * SEG);
                float h = 2.0f, l = -2.0f;
                for (int i = 0; i < 16; ++i) {
                    float4 q = gv[i];
                    h = dstep(h, q.x); l = dstep(l, q.x);
                    h = dstep(h, q.y); l = dstep(l, q.y);
                    h = dstep(h, q.z); l = dstep(l, q.z);
                    h = dstep(h, q.w); l = dstep(l, q.w);
                }
                if (h == l) { d = h; startSeg = v; break; }
                --v;
            }
        }
        // exact replay of intermediate non-constant segments (rare; L1/L2-hot)
        for (int v = startSeg + 1; v < s; ++v) {
            const float* sv = p + (size_t)v * SEG;
            for (int i = 0; i < 64; ++i) d = dstep(d, sv[i]);
        }
        // classify own segment from registers
        #pragma unroll
        for (int i = 0; i < 64; ++i) {
            d = dstep(d, u.f[i]);
            e  |= (uint64_t)(d > LAM || d < -LAM) << i;
            gw |= (uint64_t)(d > LAM) << i;
        }
    }
    if (s == NSEG - 1) {                          // forced event at N-1: final label
        const uint64_t top = 1ull << 63;
        e |= top;
        gw = (d > 0.0f) ? (gw | top) : (gw & ~top);
    }
    ev[s] = e;
    sg[s] = gw;
}

// Fill: label_j = sign of the first event at k >= j. Per block: stage 256
// (ev,sg) words + per-word incoming carry in LDS, then write fully-coalesced
// int4 chunks resolving each label with a ctz on the event suffix mask.
__global__ __launch_bounds__(256) void k_fill(const uint64_t* __restrict__ ev,
        const uint64_t* __restrict__ sg, int* __restrict__ out) {
    __shared__ uint64_t lev[256];
    __shared__ uint64_t lsg[256];
    __shared__ int lC[256];
    const int t = threadIdx.x;
    const int b = blockIdx.x;
    const int w = b * 256 + t;

    uint64_t e = ev[w], g = sg[w];
    lev[t] = e; lsg[t] = g;
    __syncthreads();

    // carry into word w = sign of first event at any position >= 64*(w+1)
    int cur = 0; bool found = false;
    for (int v = t + 1; v < 256; ++v) {           // expected ~1 iteration
        uint64_t evv = lev[v];
        if (evv) { cur = (int)((lsg[v] >> __builtin_ctzll(evv)) & 1ull); found = true; break; }
    }
    if (!found && b + 1 < NBLK) {
        int v = (b + 1) * 256;
        while (v < NSEG) {
            uint64_t evv = ev[v];
            if (evv) { cur = (int)((sg[v] >> __builtin_ctzll(evv)) & 1ull); break; }
            ++v;                                   // terminates: word NSEG-1 bit63 forced
        }
    }
    lC[t] = cur;
    __syncthreads();

    int4* o4 = (int4*)out + (size_t)b * 4096;     // block covers 4096 int4 chunks
    #pragma unroll
    for (int i = 0; i < 16; ++i) {
        int c = i * 256 + t;                       // coalesced: consecutive lanes -> consecutive 16B
        int wl = c >> 4;                           // word within block (16 chunks/word)
        int bb = (c & 15) * 4;                     // starting bit of this chunk
        uint64_t we = lev[wl], wg = lsg[wl];       // broadcast reads (same addr across 16 lanes)
        int wc = lC[wl];
        int4 r;
        {
            uint64_t m = we >> (bb + 0);
            r.x = m ? (int)((wg >> (bb + 0 + __builtin_ctzll(m))) & 1ull) : wc;
            m = we >> (bb + 1);
            r.y = m ? (int)((wg >> (bb + 1 + __builtin_ctzll(m))) & 1ull) : wc;
            m = we >> (bb + 2);
            r.z = m ? (int)((wg >> (bb + 2 + __builtin_ctzll(m))) & 1ull) : wc;
            m = we >> (bb + 3);
            r.w = m ? (int)((wg >> (bb + 3 + __builtin_ctzll(m))) & 1ull) : wc;
        }
        o4[c] = r;
    }
}

extern "C" void kernel_launch(void* const* d_in, const int* in_sizes, int n_in,
                              void* d_out, int out_size, void* d_ws, size_t ws_size,
                              hipStream_t stream) {
    (void)in_sizes; (void)n_in; (void)out_size; (void)ws_size;
    const float* p = (const float*)d_in[0];
    int* out = (int*)d_out;
    char* ws = (char*)d_ws;
    uint64_t* ev = (uint64_t*)ws;                         // 1 MB
    uint64_t* sg = (uint64_t*)(ws + (size_t)NSEG * 8);    // 1 MB

    k_ab<<<dim3(NBLK), dim3(256), 0, stream>>>(p, ev, sg);
    k_fill<<<dim3(NBLK), dim3(256), 0, stream>>>(ev, sg, out);
}